// Round 1
// baseline (179.525 us; speedup 1.0000x reference)
//
#include <hip/hip_runtime.h>
#include <hip/hip_bf16.h>

typedef unsigned short u16;
typedef float  f32x16 __attribute__((ext_vector_type(16)));
typedef short  bf16x8 __attribute__((ext_vector_type(8)));
typedef u16    u16x8  __attribute__((ext_vector_type(8)));

#define CDIM 1024
#define HW   16384

typedef const void __attribute__((address_space(1))) gvoid;
typedef void __attribute__((address_space(3))) svoid;

__device__ __forceinline__ u16 f2bf(float f) {
    unsigned u = __float_as_uint(f);
    u += 0x7fffu + ((u >> 16) & 1u);            // RNE
    return (u16)(u >> 16);
}
__device__ __forceinline__ float bf2f(u16 h) { return __uint_as_float(((unsigned)h) << 16); }

// ---------------- K1: x(f32) -> hi(bf16), lo(bf16)  (split precision) ----------------
__global__ __launch_bounds__(256) void k_convert(const float* __restrict__ x,
                                                 u16* __restrict__ hi, u16* __restrict__ lo)
{
    const long total = (long)CDIM * HW / 4;
    const long stride = (long)gridDim.x * blockDim.x;
    for (long i = (long)blockIdx.x * blockDim.x + threadIdx.x; i < total; i += stride) {
        float4 v = ((const float4*)x)[i];
        ushort4 h, l;
        h.x = f2bf(v.x); l.x = f2bf(v.x - bf2f(h.x));
        h.y = f2bf(v.y); l.y = f2bf(v.y - bf2f(h.y));
        h.z = f2bf(v.z); l.z = f2bf(v.z - bf2f(h.z));
        h.w = f2bf(v.w); l.w = f2bf(v.w - bf2f(h.w));
        ((ushort4*)hi)[i] = h;
        ((ushort4*)lo)[i] = l;
    }
}

// ---- staging: 128x64 bf16 tile via global_load_lds(16B), XOR-swizzled SOURCE (rule #21) ----
// LDS[r][cb'] holds G[r][cb' ^ ((r&7)<<4)]; reads undo the XOR -> ~4-way residual conflicts.
__device__ __forceinline__ void stage_tile(const u16* __restrict__ g, long ld, int row0, int k0,
                                           u16* lds, int tid)
{
    const int lane = tid & 63;
    const int wq = tid >> 6;
#pragma unroll
    for (int q = 0; q < 4; ++q) {
        const int chunk = (wq << 2) + q;              // 0..15, 1 KiB each
        const int lin = (chunk << 10) + (lane << 4);  // byte offset in 16 KiB tile
        const int r  = lin >> 7;                      // row (128 B rows)
        const int cb = lin & 127;
        const int gcb = cb ^ ((r & 7) << 4);          // inverse swizzle on global source
        const u16* src = g + (long)(row0 + r) * ld + k0 + (gcb >> 1);
        __builtin_amdgcn_global_load_lds((gvoid*)src, (svoid*)(lds + (chunk << 9)), 16, 0, 0);
    }
}

__device__ __forceinline__ bf16x8 lds_frag(const u16* lds, int r, int cb)
{
    const int off = (r << 7) + (cb ^ ((r & 7) << 4));
    return *(const bf16x8*)((const char*)lds + off);
}

// ---------------- K2: E1p = H*H^T, E2p = H*L^T (split-K partials) ----------------
// 128x128 tile, BK=64, 4 waves, each 64x64 via 2x2 mfma_32x32x16_bf16. L*H^T comes from
// E2p transposed in k_symmetrize (saves 1/3 of MFMA work + the L_I staging).
__global__ __launch_bounds__(256) void k_energy(const u16* __restrict__ hi, const u16* __restrict__ lo,
                                                float* __restrict__ E1p, float* __restrict__ E2p,
                                                int kchunk)
{
    __shared__ u16 sA [2][128 * 64];
    __shared__ u16 sBh[2][128 * 64];
    __shared__ u16 sBl[2][128 * 64];

    const int tid = threadIdx.x;
    const int bj = blockIdx.x, bi = blockIdx.y, ks = blockIdx.z;
    const int k0 = ks * kchunk;
    const int nsteps = kchunk >> 6;
    const int lane = tid & 63, w = tid >> 6;
    const int wm = w >> 1, wn = w & 1;
    const int l31 = lane & 31;
    const int lh  = (lane >> 5) << 4;   // byte offset of k-half within 32B k-slice

    f32x16 acc1[2][2], acc2[2][2];
    f32x16 z;
#pragma unroll
    for (int q = 0; q < 16; ++q) z[q] = 0.f;
#pragma unroll
    for (int m = 0; m < 2; ++m)
#pragma unroll
        for (int n = 0; n < 2; ++n) { acc1[m][n] = z; acc2[m][n] = z; }

    stage_tile(hi, HW, bi * 128, k0, sA[0],  tid);
    stage_tile(hi, HW, bj * 128, k0, sBh[0], tid);
    stage_tile(lo, HW, bj * 128, k0, sBl[0], tid);
    asm volatile("s_waitcnt vmcnt(0)" ::: "memory");
    __syncthreads();

    int buf = 0;
    for (int t = 0; t < nsteps; ++t) {
        if (t + 1 < nsteps) {
            const int kn = k0 + ((t + 1) << 6);
            stage_tile(hi, HW, bi * 128, kn, sA[buf ^ 1],  tid);
            stage_tile(hi, HW, bj * 128, kn, sBh[buf ^ 1], tid);
            stage_tile(lo, HW, bj * 128, kn, sBl[buf ^ 1], tid);
        }
#pragma unroll
        for (int kk = 0; kk < 4; ++kk) {
            const int cb = (kk << 5) + lh;
            bf16x8 a0 = lds_frag(sA[buf],  wm * 64 + l31,      cb);
            bf16x8 a1 = lds_frag(sA[buf],  wm * 64 + 32 + l31, cb);
            bf16x8 b0 = lds_frag(sBh[buf], wn * 64 + l31,      cb);
            bf16x8 b1 = lds_frag(sBh[buf], wn * 64 + 32 + l31, cb);
            bf16x8 c0 = lds_frag(sBl[buf], wn * 64 + l31,      cb);
            bf16x8 c1 = lds_frag(sBl[buf], wn * 64 + 32 + l31, cb);
            acc1[0][0] = __builtin_amdgcn_mfma_f32_32x32x16_bf16(a0, b0, acc1[0][0], 0, 0, 0);
            acc1[0][1] = __builtin_amdgcn_mfma_f32_32x32x16_bf16(a0, b1, acc1[0][1], 0, 0, 0);
            acc1[1][0] = __builtin_amdgcn_mfma_f32_32x32x16_bf16(a1, b0, acc1[1][0], 0, 0, 0);
            acc1[1][1] = __builtin_amdgcn_mfma_f32_32x32x16_bf16(a1, b1, acc1[1][1], 0, 0, 0);
            acc2[0][0] = __builtin_amdgcn_mfma_f32_32x32x16_bf16(a0, c0, acc2[0][0], 0, 0, 0);
            acc2[0][1] = __builtin_amdgcn_mfma_f32_32x32x16_bf16(a0, c1, acc2[0][1], 0, 0, 0);
            acc2[1][0] = __builtin_amdgcn_mfma_f32_32x32x16_bf16(a1, c0, acc2[1][0], 0, 0, 0);
            acc2[1][1] = __builtin_amdgcn_mfma_f32_32x32x16_bf16(a1, c1, acc2[1][1], 0, 0, 0);
        }
        asm volatile("s_waitcnt vmcnt(0)" ::: "memory");
        __syncthreads();
        buf ^= 1;
    }

    float* e1 = E1p + (long)ks * (CDIM * CDIM);
    float* e2 = E2p + (long)ks * (CDIM * CDIM);
#pragma unroll
    for (int m = 0; m < 2; ++m)
#pragma unroll
        for (int n = 0; n < 2; ++n)
#pragma unroll
            for (int r = 0; r < 16; ++r) {
                // C/D layout (m101): col = lane&31, row = (r&3) + 8*(r>>2) + 4*(lane>>5)
                const int row = bi * 128 + wm * 64 + m * 32 + (r & 3) + ((r >> 2) << 3) + ((lane >> 5) << 2);
                const int col = bj * 128 + wn * 64 + n * 32 + l31;
                const long idx = (long)row * CDIM + col;
                e1[idx] = acc1[m][n][r];
                e2[idx] = acc2[m][n][r];
            }
}

// ---------------- K2b: Esym = sum_ks E1p + E2p + E2p^T ----------------
__global__ __launch_bounds__(256) void k_symmetrize(const float* __restrict__ E1p,
                                                    const float* __restrict__ E2p,
                                                    float* __restrict__ Esym, int nsplit)
{
    __shared__ float tr[64][65];
    const int jb = blockIdx.x, ib = blockIdx.y, tid = threadIdx.x;
    float4 accv[4];
#pragma unroll
    for (int e4 = 0; e4 < 4; ++e4) {
        const int e = tid + (e4 << 8);
        const int i = e >> 4, j4 = (e & 15) << 2;
        float ax = 0, ay = 0, az = 0, aw = 0, bx = 0, by = 0, bz = 0, bw = 0;
        for (int ks = 0; ks < nsplit; ++ks) {
            const long base = (long)ks * (CDIM * CDIM);
            float4 p1 = *(const float4*)(E1p + base + (long)(ib * 64 + i) * CDIM + jb * 64 + j4);
            float4 p2 = *(const float4*)(E2p + base + (long)(ib * 64 + i) * CDIM + jb * 64 + j4);
            float4 p3 = *(const float4*)(E2p + base + (long)(jb * 64 + i) * CDIM + ib * 64 + j4);
            ax += p1.x + p2.x; ay += p1.y + p2.y; az += p1.z + p2.z; aw += p1.w + p2.w;
            bx += p3.x; by += p3.y; bz += p3.z; bw += p3.w;
        }
        accv[e4] = make_float4(ax, ay, az, aw);
        tr[i][j4 + 0] = bx; tr[i][j4 + 1] = by; tr[i][j4 + 2] = bz; tr[i][j4 + 3] = bw;
    }
    __syncthreads();
#pragma unroll
    for (int e4 = 0; e4 < 4; ++e4) {
        const int e = tid + (e4 << 8);
        const int i = e >> 4, j4 = (e & 15) << 2;
        float4 o = accv[e4];
        o.x += tr[j4 + 0][i]; o.y += tr[j4 + 1][i]; o.z += tr[j4 + 2][i]; o.w += tr[j4 + 3][i];
        *(float4*)(Esym + (long)(ib * 64 + i) * CDIM + jb * 64 + j4) = o;
    }
}

// ---------------- K2c: hiT = hi^T (so K4 has both operands k-contiguous) ----------------
__global__ __launch_bounds__(256) void k_transpose(const u16* __restrict__ hi, u16* __restrict__ hiT)
{
    __shared__ u16 tile[64][72];
    const int kb = blockIdx.x, cb = blockIdx.y, tid = threadIdx.x;
#pragma unroll
    for (int e4 = 0; e4 < 2; ++e4) {
        const int e = tid + (e4 << 8);
        const int i = e >> 3, j8 = (e & 7) << 3;
        u16x8 v = *(const u16x8*)(hi + (long)(cb * 64 + i) * HW + kb * 64 + j8);
        *(u16x8*)&tile[i][j8] = v;
    }
    __syncthreads();
#pragma unroll
    for (int e4 = 0; e4 < 2; ++e4) {
        const int e = tid + (e4 << 8);
        const int j = e >> 3, c8 = (e & 7) << 3;
        u16x8 v;
#pragma unroll
        for (int q = 0; q < 8; ++q) v[q] = tile[c8 + q][j];
        *(u16x8*)(hiT + (long)(kb * 64 + j) * CDIM + cb * 64 + c8) = v;
    }
}

// ---------------- K3: att = softmax(-E) rows, stored bf16 ----------------
__global__ __launch_bounds__(256) void k_softmax(const float* __restrict__ E, u16* __restrict__ att)
{
    __shared__ float red[4];
    __shared__ float bcast;
    const int row = blockIdx.x, tid = threadIdx.x;
    const float4 v = ((const float4*)(E + (long)row * CDIM))[tid];

    float m = fminf(fminf(v.x, v.y), fminf(v.z, v.w));
#pragma unroll
    for (int s = 32; s > 0; s >>= 1) m = fminf(m, __shfl_down(m, s));
    if ((tid & 63) == 0) red[tid >> 6] = m;
    __syncthreads();
    if (tid == 0) bcast = fminf(fminf(red[0], red[1]), fminf(red[2], red[3]));
    __syncthreads();
    m = bcast;  // row min of E == row max of -E

    const float px = expf(m - v.x), py = expf(m - v.y), pz = expf(m - v.z), pw = expf(m - v.w);
    float s4 = px + py + pz + pw;
#pragma unroll
    for (int s = 32; s > 0; s >>= 1) s4 += __shfl_down(s4, s);
    if ((tid & 63) == 0) red[tid >> 6] = s4;
    __syncthreads();
    if (tid == 0) bcast = red[0] + red[1] + red[2] + red[3];
    __syncthreads();
    const float inv = 1.0f / bcast;

    ushort4 o;
    o.x = f2bf(px * inv); o.y = f2bf(py * inv); o.z = f2bf(pz * inv); o.w = f2bf(pw * inv);
    ((ushort4*)(att + (long)row * CDIM))[tid] = o;
}

// ---------------- K4: out = gamma * (att @ q) + x ----------------
// C2[i,p] = dot(att_row_i, qT_row_p): same B^T GEMM structure as K2, K=1024.
__global__ __launch_bounds__(256) void k_out(const u16* __restrict__ att, const u16* __restrict__ qT,
                                             const float* __restrict__ x, const float* __restrict__ gamma,
                                             float* __restrict__ out)
{
    __shared__ u16 sA[2][128 * 64];
    __shared__ u16 sB[2][128 * 64];
    const int tid = threadIdx.x;
    const int bp = blockIdx.x, bi = blockIdx.y;
    const int lane = tid & 63, w = tid >> 6;
    const int wm = w >> 1, wn = w & 1;
    const int l31 = lane & 31;
    const int lh  = (lane >> 5) << 4;

    f32x16 acc[2][2];
    f32x16 z;
#pragma unroll
    for (int q = 0; q < 16; ++q) z[q] = 0.f;
#pragma unroll
    for (int m = 0; m < 2; ++m)
#pragma unroll
        for (int n = 0; n < 2; ++n) acc[m][n] = z;

    stage_tile(att, CDIM, bi * 128, 0, sA[0], tid);
    stage_tile(qT,  CDIM, bp * 128, 0, sB[0], tid);
    asm volatile("s_waitcnt vmcnt(0)" ::: "memory");
    __syncthreads();

    int buf = 0;
    for (int t = 0; t < 16; ++t) {
        if (t < 15) {
            stage_tile(att, CDIM, bi * 128, (t + 1) << 6, sA[buf ^ 1], tid);
            stage_tile(qT,  CDIM, bp * 128, (t + 1) << 6, sB[buf ^ 1], tid);
        }
#pragma unroll
        for (int kk = 0; kk < 4; ++kk) {
            const int cb = (kk << 5) + lh;
            bf16x8 a0 = lds_frag(sA[buf], wm * 64 + l31,      cb);
            bf16x8 a1 = lds_frag(sA[buf], wm * 64 + 32 + l31, cb);
            bf16x8 b0 = lds_frag(sB[buf], wn * 64 + l31,      cb);
            bf16x8 b1 = lds_frag(sB[buf], wn * 64 + 32 + l31, cb);
            acc[0][0] = __builtin_amdgcn_mfma_f32_32x32x16_bf16(a0, b0, acc[0][0], 0, 0, 0);
            acc[0][1] = __builtin_amdgcn_mfma_f32_32x32x16_bf16(a0, b1, acc[0][1], 0, 0, 0);
            acc[1][0] = __builtin_amdgcn_mfma_f32_32x32x16_bf16(a1, b0, acc[1][0], 0, 0, 0);
            acc[1][1] = __builtin_amdgcn_mfma_f32_32x32x16_bf16(a1, b1, acc[1][1], 0, 0, 0);
        }
        asm volatile("s_waitcnt vmcnt(0)" ::: "memory");
        __syncthreads();
        buf ^= 1;
    }

    const float g = gamma[0];
#pragma unroll
    for (int m = 0; m < 2; ++m)
#pragma unroll
        for (int n = 0; n < 2; ++n)
#pragma unroll
            for (int r = 0; r < 16; ++r) {
                const int i = bi * 128 + wm * 64 + m * 32 + (r & 3) + ((r >> 2) << 3) + ((lane >> 5) << 2);
                const int p = bp * 128 + wn * 64 + n * 32 + l31;
                const long idx = (long)i * HW + p;
                out[idx] = g * acc[m][n][r] + x[idx];
            }
}

extern "C" void kernel_launch(void* const* d_in, const int* in_sizes, int n_in,
                              void* d_out, int out_size, void* d_ws, size_t ws_size,
                              hipStream_t stream)
{
    (void)in_sizes; (void)n_in; (void)out_size;
    const float* x = (const float*)d_in[0];
    const float* gamma = (const float*)d_in[1];
    float* out = (float*)d_out;
    char* ws = (char*)d_ws;

    // Workspace layout (102 MiB with split-K=4; falls back to 78 MiB with split-K=1)
    u16* hi = (u16*)ws;                          // 32 MiB
    u16* lo = (u16*)(ws + (32ull << 20));        // 32 MiB, reused as hiT after k_energy
    int nsplit = 4;
    const size_t need4 = (64ull << 20) + 2ull * 4 * (4ull << 20) + (4ull << 20) + (2ull << 20);
    if (ws_size < need4) nsplit = 1;
    size_t off = (64ull << 20);
    float* E1p  = (float*)(ws + off); off += (size_t)nsplit * (4ull << 20);
    float* E2p  = (float*)(ws + off); off += (size_t)nsplit * (4ull << 20);
    float* Esym = (float*)(ws + off); off += (4ull << 20);
    u16*   att  = (u16*)(ws + off);

    k_convert<<<2048, 256, 0, stream>>>(x, hi, lo);
    k_energy<<<dim3(8, 8, nsplit), 256, 0, stream>>>(hi, lo, E1p, E2p, HW / nsplit);
    k_symmetrize<<<dim3(16, 16), 256, 0, stream>>>(E1p, E2p, Esym, nsplit);
    k_transpose<<<dim3(256, 16), 256, 0, stream>>>(hi, lo /* -> hiT */);
    k_softmax<<<1024, 256, 0, stream>>>(Esym, att);
    k_out<<<dim3(128, 8), 256, 0, stream>>>(att, lo /* hiT */, x, gamma, out);
}